// Round 7
// baseline (544.689 us; speedup 1.0000x reference)
//
#include <hip/hip_runtime.h>
#include <hip/hip_fp16.h>
#include <cstdint>
#include <cstddef>

#define N_NODES 100000
#define N_EDGES 1600000
#define D 128
#define NLAYERS 3
#define NB 3125       // buckets of 32 nodes
#define NBLK_E 128    // edge-phase blocks
#define EPB 12500     // edges per block: 1600000/128
#define ENT_CAP 1024  // fill2 LDS entries; bucket max ~600 (22 sigma)

typedef float f2v __attribute__((ext_vector_type(2)));
typedef float f4v __attribute__((ext_vector_type(4)));
typedef _Float16 f16x8 __attribute__((ext_vector_type(8)));
typedef float f32x4 __attribute__((ext_vector_type(4)));

// ---------------- CSR build: LDS-histogram counting sort (no global atomics) ----------------

__global__ __launch_bounds__(512) void hist1_kernel(const int* __restrict__ col,
                                                    int* __restrict__ hmat) {
    __shared__ int hist[NB];
    int b = blockIdx.x, t = threadIdx.x;
    for (int j = t; j < NB; j += 512) hist[j] = 0;
    __syncthreads();
    int base = b * EPB;
    for (int i = t; i < EPB; i += 512) {
        int c = col[base + i];
        atomicAdd(&hist[c >> 5], 1);  // LDS atomic
    }
    __syncthreads();
    for (int j = t; j < NB; j += 512) hmat[b * NB + j] = hist[j];
}

__global__ void btot_kernel(const int* __restrict__ hmat, int* __restrict__ btot) {
    int j = blockIdx.x * 256 + threadIdx.x;
    if (j < NB) {
        int s = 0;
        for (int b = 0; b < NBLK_E; b++) s += hmat[b * NB + j];
        btot[j] = s;
    }
}

// Single-block exclusive scan over 3125 bucket totals -> bstart (+ sentinel).
__global__ void bscan_kernel(const int* __restrict__ btot, int* __restrict__ bstart, int nb, int e) {
    __shared__ int lsum[1024];
    int t = threadIdx.x;
    int vals[4];
    int v0 = 0;
#pragma unroll
    for (int j = 0; j < 4; j++) {
        int idx = t * 4 + j;
        int c = (idx < nb) ? btot[idx] : 0;
        vals[j] = c;
        v0 += c;
    }
    lsum[t] = v0;
    __syncthreads();
    for (int off = 1; off < 1024; off <<= 1) {
        int x = (t >= off) ? lsum[t - off] : 0;
        __syncthreads();
        lsum[t] += x;
        __syncthreads();
    }
    int base = lsum[t] - v0;  // exclusive
#pragma unroll
    for (int j = 0; j < 4; j++) {
        int idx = t * 4 + j;
        if (idx < nb) {
            bstart[idx] = base;
            base += vals[j];
        }
    }
    if (t == 0) bstart[nb] = e;
}

// Per-(block,bucket) start offsets: hoff[b][j] = bstart[j] + sum_{b'<b} hmat[b'][j]
__global__ void hoff_kernel(const int* __restrict__ hmat, const int* __restrict__ bstart,
                            int* __restrict__ hoff) {
    int j = blockIdx.x * 256 + threadIdx.x;
    if (j < NB) {
        int run = bstart[j];
        for (int b = 0; b < NBLK_E; b++) {
            hoff[b * NB + j] = run;
            run += hmat[b * NB + j];
        }
    }
}

// Scatter edges to exact bucket-sorted positions. LDS cursors, no global atomics.
__global__ __launch_bounds__(512) void scatter_kernel(const int* __restrict__ row,
                                                      const int* __restrict__ col,
                                                      const int* __restrict__ hoff,
                                                      unsigned* __restrict__ bucketbuf) {
    __shared__ int cur[NB];
    int b = blockIdx.x, t = threadIdx.x;
    for (int j = t; j < NB; j += 512) cur[j] = hoff[b * NB + j];
    __syncthreads();
    int base = b * EPB;
    for (int i = t; i < EPB; i += 512) {
        int r = row[base + i], c = col[base + i];
        int pos = atomicAdd(&cur[c >> 5], 1);  // LDS atomic
        bucketbuf[pos] = ((unsigned)r << 5) | (unsigned)(c & 31);
    }
}

// One block per bucket: LDS histogram of 32 local cols -> per-node offsets,
// dinv, and localized CSR scatter (contiguous ~2KB range, LDS cursors).
__global__ void fill2_kernel(const unsigned* __restrict__ bucketbuf, const int* __restrict__ bstart,
                             int* __restrict__ offsets, float* __restrict__ dinv,
                             int* __restrict__ src, int n, int e) {
    __shared__ unsigned ent[ENT_CAP];
    __shared__ int hist[32];
    __shared__ int cur[32];
    __shared__ int loff[32];
    int b = blockIdx.x, t = threadIdx.x;
    int s0 = bstart[b];
    int cnt = bstart[b + 1] - s0;
    if (cnt > ENT_CAP) cnt = ENT_CAP;
    if (t < 32) hist[t] = 0;
    __syncthreads();
    for (int i = t; i < cnt; i += 256) {
        unsigned v = bucketbuf[s0 + i];
        ent[i] = v;
        atomicAdd(&hist[v & 31], 1);
    }
    __syncthreads();
    if (t == 0) {
        int run = s0;
#pragma unroll
        for (int j = 0; j < 32; j++) {
            loff[j] = run;
            run += hist[j];
        }
    }
    __syncthreads();
    if (t < 32) {
        int node = b * 32 + t;
        int o = loff[t];
        offsets[node] = o;
        cur[t] = o;
        dinv[node] = rsqrtf((float)(hist[t] + 1));  // +1 self loop
    }
    if (b == 0 && t == 0) offsets[n] = e;
    __syncthreads();
    for (int i = t; i < cnt; i += 256) {
        unsigned v = ent[i];
        int pos = atomicAdd(&cur[v & 31], 1);
        src[pos] = (int)(v >> 5);
    }
}

// ---------------- per-layer kernels ----------------

// Cast + pre-scale: xs[v] = fp16(dinv[v] * emb[v]). Pre-scaling removes the
// per-edge dinv[src] gather + multiply from the agg inner loop.
__global__ void cast_kernel(const float2* __restrict__ in, const float* __restrict__ dinv,
                            __half2* __restrict__ out, int n2) {
    int i = blockIdx.x * 256 + threadIdx.x;
    if (i < n2) {
        float d = dinv[i >> 6];  // wave-uniform (64 half2 per node)
        float2 v = in[i];
        out[i] = __floats2half2_rn(d * v.x, d * v.y);
    }
}

// W pre-split for the hi/lo fp16 MFMA: WhT/WlT[l][col][k] (transposed,
// fragment-ready). w = wh + wl with wh=fp16(w), wl=fp16(w-wh): 22-bit
// combined mantissa -> GEMM error ~2^-20, far below the fp16-gather noise.
__global__ void wsplit_kernel(const float* __restrict__ W,
                              _Float16* __restrict__ Wh, _Float16* __restrict__ Wl) {
    int c = blockIdx.x, l = blockIdx.y, k = threadIdx.x;  // 128 threads
    float w = W[(size_t)l * 16384 + k * 128 + c];
    _Float16 h = (_Float16)w;
    float r = w - (float)h;
    Wh[(size_t)l * 16384 + c * 128 + k] = h;
    Wl[(size_t)l * 16384 + c * 128 + k] = (_Float16)r;
}

// FUSED aggregate + GEMM + bias + relu. One wave per 16 target rows.
// R6 post-mortem: v1 of this fusion READ AND WROTE the same xs buffer ->
// cross-block race (block A overwrites rows block B is still gathering).
// Fix: xs is double-buffered (xs_in != xs_out, ping-pong per layer). The
// kernel body is unchanged from the R6 attempt.
// Phase 1: aggregate each row exactly as the old agg_kernel (8-deep MLP
//   gather from pre-scaled xs_in, fp32 accum), deposit hi/lo fp16 planes
//   into an 8.5KB LDS tile in MFMA-fragment layout (pitch 136 f16 = 272B:
//   both agg-writes and b128 frag-reads <=2-way bank-aliased = free, m136).
// Phase 2: R5-verified hi/lo 16x16x32 MFMA (ah.bh + al.bh + ah.bl),
//   B-frags straight from global WhT/WlT ([col][k], L2-hot 64KB).
// launch_bounds(64,4): cap VGPR at 128 -> 16 waves/CU; gather is BW-bound,
// needs ~3KB in flight/CU (has 32KB), so the occupancy drop is safe.
__global__ __launch_bounds__(64, 4) void agg_gemm_kernel(
    const __half2* __restrict__ xs_in, const int* __restrict__ offs,
    const int* __restrict__ src, const float* __restrict__ dinv,
    const _Float16* __restrict__ Whp, const _Float16* __restrict__ Wlp,  // [col][k]
    const float* __restrict__ bias, float* __restrict__ out,
    __half2* __restrict__ xs_out, int write_h, int write_out) {
    __shared__ _Float16 sA[2][16][136];  // [plane][row][16 kg * 8 + 8 pad]
    int f = threadIdx.x;  // 0..63
    int r0 = blockIdx.x * 16;

    // ---- phase 1: aggregate 16 rows (lane f owns feature pair 2f,2f+1) ----
#pragma unroll 1
    for (int lr = 0; lr < 16; lr++) {
        int v = r0 + lr;
        float dv = dinv[v];
        float2 a0 = __half22float2(xs_in[(size_t)v * 64 + f]);  // self (pre-scaled)
        float ax = a0.x;
        float ay = a0.y;
        int i = offs[v], s1 = offs[v + 1];
        for (; i + 7 < s1; i += 8) {
            int s[8];
#pragma unroll
            for (int j = 0; j < 8; j++) s[j] = src[i + j];
            float2 x[8];
#pragma unroll
            for (int j = 0; j < 8; j++) x[j] = __half22float2(xs_in[(size_t)s[j] * 64 + f]);
#pragma unroll
            for (int j = 0; j < 8; j++) {
                ax += x[j].x;
                ay += x[j].y;
            }
        }
        if (i < s1) {  // masked tail group
            int last = s1 - 1;
            int s[8];
            float m[8];
#pragma unroll
            for (int j = 0; j < 8; j++) {
                int idx = i + j;
                bool in = idx < s1;
                s[j] = src[in ? idx : last];
                m[j] = in ? 1.0f : 0.0f;
            }
            float2 x[8];
#pragma unroll
            for (int j = 0; j < 8; j++) x[j] = __half22float2(xs_in[(size_t)s[j] * 64 + f]);
#pragma unroll
            for (int j = 0; j < 8; j++) {
                ax += m[j] * x[j].x;
                ay += m[j] * x[j].y;
            }
        }
        float rx = dv * ax, ry = dv * ay;
        __half2 h2 = __floats2half2_rn(rx, ry);
        float2 hb = __half22float2(h2);
        __half2 l2 = __floats2half2_rn(rx - hb.x, ry - hb.y);
        *(unsigned*)&sA[0][lr][2 * f] = __builtin_bit_cast(unsigned, h2);
        *(unsigned*)&sA[1][lr][2 * f] = __builtin_bit_cast(unsigned, l2);
    }
    __syncthreads();  // single wave: just orders LDS writes before frag reads

    // ---- phase 2: MFMA 16x128 = sA(16x128) @ W(128x128), hi/lo 3-term ----
    int lrow = f & 15, kg = f >> 4;
    f32x4 acc[8];
#pragma unroll
    for (int nf = 0; nf < 8; nf++) acc[nf] = (f32x4){0.f, 0.f, 0.f, 0.f};

#pragma unroll
    for (int ks = 0; ks < 4; ks++) {
        int g = ks * 4 + kg;  // 8-element k-group index (k = g*8 + j)
        f16x8 ah = *(const f16x8*)&sA[0][lrow][g * 8];
        f16x8 al = *(const f16x8*)&sA[1][lrow][g * 8];
#pragma unroll
        for (int nf = 0; nf < 8; nf++) {
            int col = nf * 16 + lrow;
            f16x8 bh = *(const f16x8*)&Whp[(size_t)col * 128 + g * 8];
            acc[nf] = __builtin_amdgcn_mfma_f32_16x16x32_f16(ah, bh, acc[nf], 0, 0, 0);
            acc[nf] = __builtin_amdgcn_mfma_f32_16x16x32_f16(al, bh, acc[nf], 0, 0, 0);
        }
#pragma unroll
        for (int nf = 0; nf < 8; nf++) {
            int col = nf * 16 + lrow;
            f16x8 bl = *(const f16x8*)&Wlp[(size_t)col * 128 + g * 8];
            acc[nf] = __builtin_amdgcn_mfma_f32_16x16x32_f16(ah, bl, acc[nf], 0, 0, 0);
        }
    }

    // ---- epilogue: bias + relu; C/D frag: col=lane&15, row=(lane>>4)*4+reg ----
    float bcol[8];
#pragma unroll
    for (int nf = 0; nf < 8; nf++) bcol[nf] = bias[nf * 16 + lrow];
    int rbase = r0 + kg * 4;
#pragma unroll
    for (int j = 0; j < 4; j++) {
        int rowi = rbase + j;
        float dvr = write_h ? dinv[rowi] : 0.f;
#pragma unroll
        for (int nf = 0; nf < 8; nf++) {
            float o = fmaxf(acc[nf][j] + bcol[nf], 0.f);
            float o2 = __shfl_xor(o, 1);  // partner col (lane^1): same row, col^1
            int col = nf * 16 + lrow;
            if (write_out)
                __builtin_nontemporal_store(o, out + (size_t)rowi * 128 + col);
            if (write_h && !(f & 1))
                xs_out[(size_t)rowi * 64 + (col >> 1)] =
                    __floats2half2_rn(dvr * o, dvr * o2);
        }
    }
}

// ---------------- launch ----------------

extern "C" void kernel_launch(void* const* d_in, const int* in_sizes, int n_in,
                              void* d_out, int out_size, void* d_ws, size_t ws_size,
                              hipStream_t stream) {
    const int* edge = (const int*)d_in[0];   // [2, E] int32
    const float* emb = (const float*)d_in[1];
    const float* Ws = (const float*)d_in[2]; // [L, D, D]
    const float* bs = (const float*)d_in[3]; // [L, D]
    float* out = (float*)d_out;

    const int n = N_NODES, e = N_EDGES;
    const int* row = edge;       // sources
    const int* col = edge + e;   // targets

    char* p = (char*)d_ws;
    __half2* xsA = (__half2*)p;               // 25.6 MB (pre-scaled fp16 features, buf A)
    unsigned* bucketbuf = (unsigned*)p;       // aliases xsA: dead before cast runs
    p += (size_t)n * D * 2;
    __half2* xsB = (__half2*)p;               // 25.6 MB (buf B — fusion needs ping-pong:
    p += (size_t)n * D * 2;                   //  same-buffer read+write raced in R6 v1)
    int* csr_src  = (int*)p;    p += (size_t)e * 4;           // 6.4 MB
    float* dinv   = (float*)p;  p += (size_t)n * 4;
    int* offsets  = (int*)p;    p += (size_t)(n + 1) * 4;
    int* btot     = (int*)p;    p += (size_t)NB * 4;
    int* bstart   = (int*)p;    p += (size_t)(NB + 1) * 4;
    int* hmat     = (int*)p;    p += (size_t)NBLK_E * NB * 4; // 1.6 MB
    int* hoff     = (int*)p;    p += (size_t)NBLK_E * NB * 4; // 1.6 MB
    _Float16* WhT = (_Float16*)p; p += (size_t)NLAYERS * D * D * 2;  // 98 KB
    _Float16* WlT = (_Float16*)p; p += (size_t)NLAYERS * D * D * 2;  // 98 KB

    hist1_kernel<<<NBLK_E, 512, 0, stream>>>(col, hmat);
    btot_kernel<<<(NB + 255) / 256, 256, 0, stream>>>(hmat, btot);
    bscan_kernel<<<1, 1024, 0, stream>>>(btot, bstart, NB, e);
    hoff_kernel<<<(NB + 255) / 256, 256, 0, stream>>>(hmat, bstart, hoff);
    scatter_kernel<<<NBLK_E, 512, 0, stream>>>(row, col, hoff, bucketbuf);
    fill2_kernel<<<NB, 256, 0, stream>>>(bucketbuf, bstart, offsets, dinv, csr_src, n, e);
    wsplit_kernel<<<dim3(128, NLAYERS), 128, 0, stream>>>(Ws, WhT, WlT);

    int n2 = n * 64;  // half2 count
    cast_kernel<<<(n2 + 255) / 256, 256, 0, stream>>>((const float2*)emb, dinv, xsA, n2);

    __half2* xin = xsA;
    __half2* xout = xsB;
    for (int l = 0; l < NLAYERS; l++) {
        agg_gemm_kernel<<<n / 16, 64, 0, stream>>>(
            xin, offsets, csr_src, dinv,
            WhT + (size_t)l * D * D, WlT + (size_t)l * D * D,
            bs + (size_t)l * D, out, xout,
            (l < NLAYERS - 1) ? 1 : 0, (l == NLAYERS - 1) ? 1 : 0);
        __half2* tmp = xin; xin = xout; xout = tmp;
    }
}

// Round 8
// 496.277 us; speedup vs baseline: 1.0976x; 1.0976x over previous
//
#include <hip/hip_runtime.h>
#include <hip/hip_fp16.h>
#include <cstdint>
#include <cstddef>

#define N_NODES 100000
#define N_EDGES 1600000
#define D 128
#define NLAYERS 3
#define NB 3125       // buckets of 32 nodes
#define NBLK_E 128    // edge-phase blocks
#define EPB 12500     // edges per block: 1600000/128
#define ENT_CAP 1024  // fill2 LDS entries; bucket max ~600 (22 sigma)

typedef float f2v __attribute__((ext_vector_type(2)));
typedef float f4v __attribute__((ext_vector_type(4)));
typedef _Float16 f16x8 __attribute__((ext_vector_type(8)));
typedef float f32x4 __attribute__((ext_vector_type(4)));

// ---------------- CSR build: LDS-histogram counting sort (no global atomics) ----------------

__global__ __launch_bounds__(512) void hist1_kernel(const int* __restrict__ col,
                                                    int* __restrict__ hmat) {
    __shared__ int hist[NB];
    int b = blockIdx.x, t = threadIdx.x;
    for (int j = t; j < NB; j += 512) hist[j] = 0;
    __syncthreads();
    int base = b * EPB;
    for (int i = t; i < EPB; i += 512) {
        int c = col[base + i];
        atomicAdd(&hist[c >> 5], 1);  // LDS atomic
    }
    __syncthreads();
    for (int j = t; j < NB; j += 512) hmat[b * NB + j] = hist[j];
}

__global__ void btot_kernel(const int* __restrict__ hmat, int* __restrict__ btot) {
    int j = blockIdx.x * 256 + threadIdx.x;
    if (j < NB) {
        int s = 0;
        for (int b = 0; b < NBLK_E; b++) s += hmat[b * NB + j];
        btot[j] = s;
    }
}

// Single-block exclusive scan over 3125 bucket totals -> bstart (+ sentinel).
__global__ void bscan_kernel(const int* __restrict__ btot, int* __restrict__ bstart, int nb, int e) {
    __shared__ int lsum[1024];
    int t = threadIdx.x;
    int vals[4];
    int v0 = 0;
#pragma unroll
    for (int j = 0; j < 4; j++) {
        int idx = t * 4 + j;
        int c = (idx < nb) ? btot[idx] : 0;
        vals[j] = c;
        v0 += c;
    }
    lsum[t] = v0;
    __syncthreads();
    for (int off = 1; off < 1024; off <<= 1) {
        int x = (t >= off) ? lsum[t - off] : 0;
        __syncthreads();
        lsum[t] += x;
        __syncthreads();
    }
    int base = lsum[t] - v0;  // exclusive
#pragma unroll
    for (int j = 0; j < 4; j++) {
        int idx = t * 4 + j;
        if (idx < nb) {
            bstart[idx] = base;
            base += vals[j];
        }
    }
    if (t == 0) bstart[nb] = e;
}

// Per-(block,bucket) start offsets: hoff[b][j] = bstart[j] + sum_{b'<b} hmat[b'][j]
__global__ void hoff_kernel(const int* __restrict__ hmat, const int* __restrict__ bstart,
                            int* __restrict__ hoff) {
    int j = blockIdx.x * 256 + threadIdx.x;
    if (j < NB) {
        int run = bstart[j];
        for (int b = 0; b < NBLK_E; b++) {
            hoff[b * NB + j] = run;
            run += hmat[b * NB + j];
        }
    }
}

// Scatter edges to exact bucket-sorted positions. LDS cursors, no global atomics.
__global__ __launch_bounds__(512) void scatter_kernel(const int* __restrict__ row,
                                                      const int* __restrict__ col,
                                                      const int* __restrict__ hoff,
                                                      unsigned* __restrict__ bucketbuf) {
    __shared__ int cur[NB];
    int b = blockIdx.x, t = threadIdx.x;
    for (int j = t; j < NB; j += 512) cur[j] = hoff[b * NB + j];
    __syncthreads();
    int base = b * EPB;
    for (int i = t; i < EPB; i += 512) {
        int r = row[base + i], c = col[base + i];
        int pos = atomicAdd(&cur[c >> 5], 1);  // LDS atomic
        bucketbuf[pos] = ((unsigned)r << 5) | (unsigned)(c & 31);
    }
}

// One block per bucket: LDS histogram of 32 local cols -> per-node offsets,
// dinv, and localized CSR scatter (contiguous ~2KB range, LDS cursors).
__global__ void fill2_kernel(const unsigned* __restrict__ bucketbuf, const int* __restrict__ bstart,
                             int* __restrict__ offsets, float* __restrict__ dinv,
                             int* __restrict__ src, int n, int e) {
    __shared__ unsigned ent[ENT_CAP];
    __shared__ int hist[32];
    __shared__ int cur[32];
    __shared__ int loff[32];
    int b = blockIdx.x, t = threadIdx.x;
    int s0 = bstart[b];
    int cnt = bstart[b + 1] - s0;
    if (cnt > ENT_CAP) cnt = ENT_CAP;
    if (t < 32) hist[t] = 0;
    __syncthreads();
    for (int i = t; i < cnt; i += 256) {
        unsigned v = bucketbuf[s0 + i];
        ent[i] = v;
        atomicAdd(&hist[v & 31], 1);
    }
    __syncthreads();
    if (t == 0) {
        int run = s0;
#pragma unroll
        for (int j = 0; j < 32; j++) {
            loff[j] = run;
            run += hist[j];
        }
    }
    __syncthreads();
    if (t < 32) {
        int node = b * 32 + t;
        int o = loff[t];
        offsets[node] = o;
        cur[t] = o;
        dinv[node] = rsqrtf((float)(hist[t] + 1));  // +1 self loop
    }
    if (b == 0 && t == 0) offsets[n] = e;
    __syncthreads();
    for (int i = t; i < cnt; i += 256) {
        unsigned v = ent[i];
        int pos = atomicAdd(&cur[v & 31], 1);
        src[pos] = (int)(v >> 5);
    }
}

// ---------------- per-layer kernels ----------------

// Cast + pre-scale: xs[v] = fp16(dinv[v] * emb[v]). Pre-scaling removes the
// per-edge dinv[src] gather + multiply from the agg inner loop.
__global__ void cast_kernel(const float2* __restrict__ in, const float* __restrict__ dinv,
                            __half2* __restrict__ out, int n2) {
    int i = blockIdx.x * 256 + threadIdx.x;
    if (i < n2) {
        float d = dinv[i >> 6];  // wave-uniform (64 half2 per node)
        float2 v = in[i];
        out[i] = __floats2half2_rn(d * v.x, d * v.y);
    }
}

// W pre-split for the hi/lo fp16 MFMA: WhT/WlT[l][col][k] (transposed,
// fragment-ready). w = wh + wl with wh=fp16(w), wl=fp16(w-wh): 22-bit
// combined mantissa -> GEMM error ~2^-20, far below the fp16-gather noise.
__global__ void wsplit_kernel(const float* __restrict__ W,
                              _Float16* __restrict__ Wh, _Float16* __restrict__ Wl) {
    int c = blockIdx.x, l = blockIdx.y, k = threadIdx.x;  // 128 threads
    float w = W[(size_t)l * 16384 + k * 128 + c];
    _Float16 h = (_Float16)w;
    float r = w - (float)h;
    Wh[(size_t)l * 16384 + c * 128 + k] = h;
    Wl[(size_t)l * 16384 + c * 128 + k] = (_Float16)r;
}

// FUSED aggregate + GEMM + bias + relu.
// R7 post-mortem: the 1-wave/16-row version halved gather MLP (11.5 waves/CU
// x 8 outstanding vs unfused agg's 24x8) -> HBM 4.15->1.74 TB/s, 127us. Fix
// is launch geometry, not structure: 256 threads / 4 waves per block.
//   Phase 1: wave w aggregates rows w*4..w*4+3 (same 8-deep MLP per row).
//   Phase 2: wave w computes col-frags nf=2w,2w+1 (32 cols) of the 16x128
//     MFMA, acc[2] only. launch_bounds(256,8) -> 32 waves/CU target, ~256
//     outstanding gathers/CU (> unfused agg's 192).
// xs double-buffered by caller (R6 race fix). LDS tile/fragment layout and
// hi/lo 3-term MFMA identical to the R7-verified kernel.
__global__ __launch_bounds__(256, 8) void agg_gemm_kernel(
    const __half2* __restrict__ xs_in, const int* __restrict__ offs,
    const int* __restrict__ src, const float* __restrict__ dinv,
    const _Float16* __restrict__ Whp, const _Float16* __restrict__ Wlp,  // [col][k]
    const float* __restrict__ bias, float* __restrict__ out,
    __half2* __restrict__ xs_out, int write_h, int write_out) {
    __shared__ _Float16 sA[2][16][136];  // [plane][row][16 kg * 8 + 8 pad]
    int t = threadIdx.x;
    int f = t & 63;   // lane
    int w = t >> 6;   // wave 0..3
    int r0 = blockIdx.x * 16;

    // ---- phase 1: wave w aggregates 4 rows (lane f owns feature pair 2f,2f+1) ----
#pragma unroll 1
    for (int q = 0; q < 4; q++) {
        int lr = w * 4 + q;
        int v = r0 + lr;
        float dv = dinv[v];
        float2 a0 = __half22float2(xs_in[(size_t)v * 64 + f]);  // self (pre-scaled)
        float ax = a0.x;
        float ay = a0.y;
        int i = offs[v], s1 = offs[v + 1];
        for (; i + 7 < s1; i += 8) {
            int s[8];
#pragma unroll
            for (int j = 0; j < 8; j++) s[j] = src[i + j];
            float2 x[8];
#pragma unroll
            for (int j = 0; j < 8; j++) x[j] = __half22float2(xs_in[(size_t)s[j] * 64 + f]);
#pragma unroll
            for (int j = 0; j < 8; j++) {
                ax += x[j].x;
                ay += x[j].y;
            }
        }
        if (i < s1) {  // masked tail group
            int last = s1 - 1;
            int s[8];
            float m[8];
#pragma unroll
            for (int j = 0; j < 8; j++) {
                int idx = i + j;
                bool in = idx < s1;
                s[j] = src[in ? idx : last];
                m[j] = in ? 1.0f : 0.0f;
            }
            float2 x[8];
#pragma unroll
            for (int j = 0; j < 8; j++) x[j] = __half22float2(xs_in[(size_t)s[j] * 64 + f]);
#pragma unroll
            for (int j = 0; j < 8; j++) {
                ax += m[j] * x[j].x;
                ay += m[j] * x[j].y;
            }
        }
        float rx = dv * ax, ry = dv * ay;
        __half2 h2 = __floats2half2_rn(rx, ry);
        float2 hb = __half22float2(h2);
        __half2 l2 = __floats2half2_rn(rx - hb.x, ry - hb.y);
        *(unsigned*)&sA[0][lr][2 * f] = __builtin_bit_cast(unsigned, h2);
        *(unsigned*)&sA[1][lr][2 * f] = __builtin_bit_cast(unsigned, l2);
    }
    __syncthreads();  // tile complete across all 4 waves

    // ---- phase 2: wave w does cols (2w)*16..(2w+1)*16+15 of the hi/lo MFMA ----
    int lrow = f & 15, kg = f >> 4;
    f32x4 acc[2];
    acc[0] = (f32x4){0.f, 0.f, 0.f, 0.f};
    acc[1] = (f32x4){0.f, 0.f, 0.f, 0.f};

#pragma unroll
    for (int ks = 0; ks < 4; ks++) {
        int g = ks * 4 + kg;  // 8-element k-group index (k = g*8 + j)
        f16x8 ah = *(const f16x8*)&sA[0][lrow][g * 8];
        f16x8 al = *(const f16x8*)&sA[1][lrow][g * 8];
#pragma unroll
        for (int c = 0; c < 2; c++) {
            int col = (w * 2 + c) * 16 + lrow;
            f16x8 bh = *(const f16x8*)&Whp[(size_t)col * 128 + g * 8];
            f16x8 bl = *(const f16x8*)&Wlp[(size_t)col * 128 + g * 8];
            acc[c] = __builtin_amdgcn_mfma_f32_16x16x32_f16(ah, bh, acc[c], 0, 0, 0);
            acc[c] = __builtin_amdgcn_mfma_f32_16x16x32_f16(al, bh, acc[c], 0, 0, 0);
            acc[c] = __builtin_amdgcn_mfma_f32_16x16x32_f16(ah, bl, acc[c], 0, 0, 0);
        }
    }

    // ---- epilogue: bias + relu; C/D frag: col=lane&15, row=(lane>>4)*4+reg ----
    float bcol[2];
    bcol[0] = bias[(w * 2 + 0) * 16 + lrow];
    bcol[1] = bias[(w * 2 + 1) * 16 + lrow];
    int rbase = r0 + kg * 4;
#pragma unroll
    for (int j = 0; j < 4; j++) {
        int rowi = rbase + j;
        float dvr = write_h ? dinv[rowi] : 0.f;
#pragma unroll
        for (int c = 0; c < 2; c++) {
            float o = fmaxf(acc[c][j] + bcol[c], 0.f);
            float o2 = __shfl_xor(o, 1);  // partner col (lane^1): same row, col^1
            int col = (w * 2 + c) * 16 + lrow;
            if (write_out)
                __builtin_nontemporal_store(o, out + (size_t)rowi * 128 + col);
            if (write_h && !(f & 1))
                xs_out[(size_t)rowi * 64 + (col >> 1)] =
                    __floats2half2_rn(dvr * o, dvr * o2);
        }
    }
}

// ---------------- launch ----------------

extern "C" void kernel_launch(void* const* d_in, const int* in_sizes, int n_in,
                              void* d_out, int out_size, void* d_ws, size_t ws_size,
                              hipStream_t stream) {
    const int* edge = (const int*)d_in[0];   // [2, E] int32
    const float* emb = (const float*)d_in[1];
    const float* Ws = (const float*)d_in[2]; // [L, D, D]
    const float* bs = (const float*)d_in[3]; // [L, D]
    float* out = (float*)d_out;

    const int n = N_NODES, e = N_EDGES;
    const int* row = edge;       // sources
    const int* col = edge + e;   // targets

    char* p = (char*)d_ws;
    __half2* xsA = (__half2*)p;               // 25.6 MB (pre-scaled fp16 features, buf A)
    unsigned* bucketbuf = (unsigned*)p;       // aliases xsA: dead before cast runs
    p += (size_t)n * D * 2;
    __half2* xsB = (__half2*)p;               // 25.6 MB (buf B — fusion needs ping-pong:
    p += (size_t)n * D * 2;                   //  same-buffer read+write races, R6)
    int* csr_src  = (int*)p;    p += (size_t)e * 4;           // 6.4 MB
    float* dinv   = (float*)p;  p += (size_t)n * 4;
    int* offsets  = (int*)p;    p += (size_t)(n + 1) * 4;
    int* btot     = (int*)p;    p += (size_t)NB * 4;
    int* bstart   = (int*)p;    p += (size_t)(NB + 1) * 4;
    int* hmat     = (int*)p;    p += (size_t)NBLK_E * NB * 4; // 1.6 MB
    int* hoff     = (int*)p;    p += (size_t)NBLK_E * NB * 4; // 1.6 MB
    _Float16* WhT = (_Float16*)p; p += (size_t)NLAYERS * D * D * 2;  // 98 KB
    _Float16* WlT = (_Float16*)p; p += (size_t)NLAYERS * D * D * 2;  // 98 KB

    hist1_kernel<<<NBLK_E, 512, 0, stream>>>(col, hmat);
    btot_kernel<<<(NB + 255) / 256, 256, 0, stream>>>(hmat, btot);
    bscan_kernel<<<1, 1024, 0, stream>>>(btot, bstart, NB, e);
    hoff_kernel<<<(NB + 255) / 256, 256, 0, stream>>>(hmat, bstart, hoff);
    scatter_kernel<<<NBLK_E, 512, 0, stream>>>(row, col, hoff, bucketbuf);
    fill2_kernel<<<NB, 256, 0, stream>>>(bucketbuf, bstart, offsets, dinv, csr_src, n, e);
    wsplit_kernel<<<dim3(128, NLAYERS), 128, 0, stream>>>(Ws, WhT, WlT);

    int n2 = n * 64;  // half2 count
    cast_kernel<<<(n2 + 255) / 256, 256, 0, stream>>>((const float2*)emb, dinv, xsA, n2);

    __half2* xin = xsA;
    __half2* xout = xsB;
    for (int l = 0; l < NLAYERS; l++) {
        agg_gemm_kernel<<<n / 16, 256, 0, stream>>>(
            xin, offsets, csr_src, dinv,
            WhT + (size_t)l * D * D, WlT + (size_t)l * D * D,
            bs + (size_t)l * D, out, xout,
            (l < NLAYERS - 1) ? 1 : 0, (l == NLAYERS - 1) ? 1 : 0);
        __half2* tmp = xin; xin = xout; xout = tmp;
    }
}